// Round 2
// baseline (117.721 us; speedup 1.0000x reference)
//
#include <hip/hip_runtime.h>
#include <math.h>

// Problem constants (from reference)
constexpr int kB = 256, kT = 8, kS = 200, kR = 8, kD = 64, kF = 20;

// ---------------------------------------------------------------------------
// Kernel 1: decay[b][r][s] = valid ? clip( sum_k cos(w_k)*fr[r,k]-sin(w_k)*fi[r,k], 0,1 )/40 : 0
// (the reference's concat over [f,-f] duplicates identical terms; mean/2 == sum/(2F))
// Layout [B][R][S] so the main kernel reads it coalesced per (b,r) row.
// ---------------------------------------------------------------------------
__global__ __launch_bounds__(256) void decay_kernel(
    const float* __restrict__ dt,   // [B,S]
    const float* __restrict__ fr,   // [R,F]
    const float* __restrict__ fi,   // [R,F]
    const int*   __restrict__ vm,   // [B,S]  (valid_mask flattened)
    float* __restrict__ dec)        // [B,R,S] out (workspace)
{
    int tid = blockIdx.x * 256 + threadIdx.x;
    if (tid >= kB * kS) return;
    int b = tid / kS, s = tid - b * kS;
    float t = dt[tid];
    bool valid = vm[tid] != 0;

    float cs[kF], sn[kF];
#pragma unroll
    for (int k = 0; k < kF; ++k) {
        float fk = (float)k * (0.5f / (float)(kF - 1));   // linspace(0,1,F)/2
        float w  = 6.283185307179586f * fk * t;
        sincosf(w, &sn[k], &cs[k]);
    }
#pragma unroll
    for (int r = 0; r < kR; ++r) {
        float acc = 0.f;
#pragma unroll
        for (int k = 0; k < kF; ++k)
            acc += cs[k] * fr[r * kF + k] - sn[k] * fi[r * kF + k];
        acc *= (1.0f / (2.0f * (float)kF));               // sum/(2F)
        acc = fminf(fmaxf(acc, 0.f), 1.f);                // clip
        dec[(b * kR + r) * kS + s] = valid ? acc : 0.f;
    }
}

// ---------------------------------------------------------------------------
// Kernel 2: one block per (b,t). 256 threads = 4 waves.
//   P0: ri[r][d] = (rel[r][d]+tv[b,t,r,d])*target[b,t,d]  -> LDS
//   P1: thread j (j<200): att_raw[r][j] = seq[b,j,:]·ri[r,:]; -inf if masked
//   P2: wave w: softmax rows r=2w,2w+1 (shfl reduce), att_e[s][r]=e/denom*decay
//   P3: wave w: s in [50w,50w+50): acc[r] += seq[b,s,lane]*att_e[s][r]
//       cross-wave reduce in LDS, coalesced store out[b,t,r,d]
// NOTE: the reference's global `att - att.max()` is shift-invariant under
// softmax -> omitted (softmax subtracts per-column max anyway).
// ---------------------------------------------------------------------------
__global__ __launch_bounds__(256) void rda_kernel(
    const float* __restrict__ seq,    // [B,S,D]
    const float* __restrict__ target, // [B,T,D]
    const float* __restrict__ tv,     // [B,T,R,D]
    const int*   __restrict__ vm,     // [B,S]
    const float* __restrict__ rel,    // [R,D]
    const float* __restrict__ dec,    // [B,R,S]
    float* __restrict__ out)          // [B,T,R,D]
{
    // att_raw (8*200 floats) and partials (4*8*64 floats) are time-disjoint -> union
    __shared__ float ri[kR * kD];            // 2 KB
    __shared__ float att_e[kS * kR];         // 6.25 KB, [s][r], rows 32B -> float4-aligned
    __shared__ float u[4 * kR * kD];         // 8 KB union: att_raw [r][200] then part [w][r][64]

    float* att_raw = u;                      // att_raw[r*kS + s], 1600 floats
    float* part    = u;                      // part[(w*kR+r)*kD + d], 2048 floats

    const int bt = blockIdx.x;               // = b*T + t
    const int b  = bt >> 3;
    const int tid = threadIdx.x;
    const int wave = tid >> 6, lane = tid & 63;

    // ---- P0: ri
    {
        int idx = tid;                       // 512 values, 2 per thread
#pragma unroll
        for (int it = 0; it < 2; ++it, idx += 256) {
            float tg = target[bt * kD + (idx & 63)];
            ri[idx] = (rel[idx] + tv[bt * kR * kD + idx]) * tg;
        }
    }
    __syncthreads();

    // ---- P1: raw scores
    if (tid < kS) {
        const int s = tid;
        const float4* seqrow = (const float4*)(seq + (size_t)(b * kS + s) * kD);
        float a[kR];
#pragma unroll
        for (int r = 0; r < kR; ++r) a[r] = 0.f;
#pragma unroll
        for (int uu = 0; uu < kD / 4; ++uu) {
            float4 sv = seqrow[uu];
#pragma unroll
            for (int r = 0; r < kR; ++r) {
                float4 rv = ((const float4*)(ri + r * kD))[uu];
                a[r] += sv.x * rv.x + sv.y * rv.y + sv.z * rv.z + sv.w * rv.w;
            }
        }
        const bool valid = vm[b * kS + s] != 0;
#pragma unroll
        for (int r = 0; r < kR; ++r)
            att_raw[r * kS + s] = valid ? a[r] : -INFINITY;
    }
    __syncthreads();

    // ---- P2: masked softmax over s per r, times decay
#pragma unroll
    for (int h = 0; h < 2; ++h) {
        const int r = 2 * wave + h;
        float a0 = att_raw[r * kS + lane];
        float a1 = att_raw[r * kS + lane + 64];
        float a2 = att_raw[r * kS + lane + 128];
        float a3 = (lane < kS - 192) ? att_raw[r * kS + lane + 192] : -INFINITY;
        float m = fmaxf(fmaxf(a0, a1), fmaxf(a2, a3));
#pragma unroll
        for (int off = 32; off; off >>= 1) m = fmaxf(m, __shfl_xor(m, off));
        float e0 = expf(a0 - m), e1 = expf(a1 - m), e2 = expf(a2 - m);
        float e3 = (lane < kS - 192) ? expf(a3 - m) : 0.f;
        float ssum = e0 + e1 + e2 + e3;
#pragma unroll
        for (int off = 32; off; off >>= 1) ssum += __shfl_xor(ssum, off);
        const float inv = 1.0f / ssum;
        const float* dr = dec + (size_t)(b * kR + r) * kS;
        att_e[(lane)       * kR + r] = e0 * inv * dr[lane];
        att_e[(lane + 64)  * kR + r] = e1 * inv * dr[lane + 64];
        att_e[(lane + 128) * kR + r] = e2 * inv * dr[lane + 128];
        if (lane < kS - 192)
            att_e[(lane + 192) * kR + r] = e3 * inv * dr[lane + 192];
    }
    __syncthreads();   // also separates att_raw (read) from part (write) union

    // ---- P3: context partials; wave w owns s in [50w, 50w+50)
    {
        float acc[kR];
#pragma unroll
        for (int r = 0; r < kR; ++r) acc[r] = 0.f;
        const int s0 = wave * 50;
        const float* seqb = seq + (size_t)b * kS * kD + lane;
        for (int s = s0; s < s0 + 50; ++s) {
            float sv = seqb[(size_t)s * kD];
            float4 e0 = *(const float4*)(att_e + s * kR);
            float4 e1 = *(const float4*)(att_e + s * kR + 4);
            acc[0] += sv * e0.x; acc[1] += sv * e0.y;
            acc[2] += sv * e0.z; acc[3] += sv * e0.w;
            acc[4] += sv * e1.x; acc[5] += sv * e1.y;
            acc[6] += sv * e1.z; acc[7] += sv * e1.w;
        }
#pragma unroll
        for (int r = 0; r < kR; ++r)
            part[(wave * kR + r) * kD + lane] = acc[r];
    }
    __syncthreads();

    // ---- P4: reduce partials, store
    {
        int idx = tid;
#pragma unroll
        for (int it = 0; it < 2; ++it, idx += 256) {
            float v = part[idx] + part[kR * kD + idx] +
                      part[2 * kR * kD + idx] + part[3 * kR * kD + idx];
            out[(size_t)bt * kR * kD + idx] = v;
        }
    }
}

extern "C" void kernel_launch(void* const* d_in, const int* in_sizes, int n_in,
                              void* d_out, int out_size, void* d_ws, size_t ws_size,
                              hipStream_t stream) {
    const float* seq    = (const float*)d_in[0];   // [B,S,D]
    const float* dt     = (const float*)d_in[1];   // [B,S]
    const float* target = (const float*)d_in[2];   // [B,T,D]
    const float* tv     = (const float*)d_in[3];   // [B,T,R,D]
    const int*   vm     = (const int*)  d_in[4];   // [B,1,S,1]
    const float* rel    = (const float*)d_in[5];   // [R,D]
    const float* fr     = (const float*)d_in[6];   // [R,F]
    const float* fi     = (const float*)d_in[7];   // [R,F]
    float* out = (float*)d_out;                    // [B,T,R,D] f32
    float* dec = (float*)d_ws;                     // [B,R,S] = 1.6 MB scratch

    decay_kernel<<<(kB * kS + 255) / 256, 256, 0, stream>>>(dt, fr, fi, vm, dec);
    rda_kernel<<<kB * kT, 256, 0, stream>>>(seq, target, tv, vm, rel, dec, out);
}

// Round 3
// 112.020 us; speedup vs baseline: 1.0509x; 1.0509x over previous
//
#include <hip/hip_runtime.h>
#include <math.h>

// Problem constants (from reference)
constexpr int kB = 256, kT = 8, kS = 200, kR = 8, kD = 64, kF = 20;
constexpr int TG = 4;                  // t's per block -> grid = B * (T/TG) = 512

// ---------------------------------------------------------------------------
// Fully fused kernel. One block per (b, t-group of 4), 256 threads = 4 waves.
//   P0 : stage fr/fi -> LDS; ri[t][r][d] = (rel+tv)*target -> LDS
//   P1 : thread s (<200): decay[r][s] (20 sincosf, T-independent) AND
//        att[t][r][s] = seq[b,s,:]·ri[t,r,:]  (valid ? . : -inf)
//   P2 : wave w owns t=w: softmax over s per r (shfl reduce), in-place
//        att[t][r][s] = e/denom * dec[r][s]
//   P3 : wave w owns t=w (no barrier needed - wave-coherent LDS):
//        lane=d, acc[r] += seq[b,s,d]*att[t][r][s] (float4 broadcasts along s),
//        direct coalesced store to out[b,t,r,:]
// NOTES:
//  - global `att - att.max()` is shift-invariant under softmax -> omitted.
//  - decay concat halves are identical: mean(2F)/2 == sum_F/(2F).
//  - block swizzle: the two blocks sharing b land on the same XCD (o%8 equal)
//    so seq[b] is fetched from HBM ~once.
// ---------------------------------------------------------------------------
__global__ __launch_bounds__(256) void rda_fused(
    const float* __restrict__ seq,    // [B,S,D]
    const float* __restrict__ dt,     // [B,S]
    const float* __restrict__ target, // [B,T,D]
    const float* __restrict__ tv,     // [B,T,R,D]
    const int*   __restrict__ vm,     // [B,S]
    const float* __restrict__ rel,    // [R,D]
    const float* __restrict__ fr,     // [R,F]
    const float* __restrict__ fi,     // [R,F]
    float* __restrict__ out)          // [B,T,R,D]
{
    __shared__ float dec[kR][kS];        // 6.4 KB  [r][s] (stride-1 in s)
    __shared__ float ri[TG * kR * kD];   // 8 KB
    __shared__ float att[TG][kR][kS];    // 25.6 KB (row base 800B -> 16B aligned)
    __shared__ float ff[2][kR][kF];      // 1.28 KB staged fr/fi

    // --- swizzled block decode: pair (b, tg=0/1) shares XCD (same o%8)
    const int o   = blockIdx.x;
    const int xcd = o & 7, q = o >> 3;
    const int tg  = q & 1;
    const int b   = xcd + 8 * (q >> 1);
    const int bt0 = b * kT + tg * TG;

    const int tid = threadIdx.x, wave = tid >> 6, lane = tid & 63;

    // ---- P0: stage fr/fi and ri
    for (int idx = tid; idx < 2 * kR * kF; idx += 256)
        ((float*)ff)[idx] = (idx < kR * kF) ? fr[idx] : fi[idx - kR * kF];
    {
        const float* tvb = tv + (size_t)bt0 * kR * kD;
        const float* tgb = target + (size_t)bt0 * kD;
        for (int idx = tid; idx < TG * kR * kD; idx += 256) {
            int t = idx >> 9;
            ri[idx] = (rel[idx & 511] + tvb[idx]) * tgb[t * kD + (idx & 63)];
        }
    }
    __syncthreads();

    // ---- P1: per-s decay + raw scores
    if (tid < kS) {
        const int s = tid;
        const bool valid = vm[b * kS + s] != 0;

        // decay (T-independent, computed once per b-block pair)
        {
            const float t = dt[b * kS + s];
            float cs[kF], sn[kF];
#pragma unroll
            for (int k = 0; k < kF; ++k) {
                float fk = (float)k * (0.5f / (float)(kF - 1));
                sincosf(6.283185307179586f * fk * t, &sn[k], &cs[k]);
            }
#pragma unroll
            for (int r = 0; r < kR; ++r) {
                float acc = 0.f;
#pragma unroll
                for (int k = 0; k < kF; ++k)
                    acc += cs[k] * ff[0][r][k] - sn[k] * ff[1][r][k];
                acc *= (1.0f / (2.0f * (float)kF));
                acc = fminf(fmaxf(acc, 0.f), 1.f);
                dec[r][s] = valid ? acc : 0.f;
            }
        }

        // scores for all 4 t's
        {
            const float4* seqrow = (const float4*)(seq + (size_t)(b * kS + s) * kD);
            float a[TG][kR];
#pragma unroll
            for (int t = 0; t < TG; ++t)
#pragma unroll
                for (int r = 0; r < kR; ++r) a[t][r] = 0.f;
#pragma unroll
            for (int uu = 0; uu < kD / 4; ++uu) {
                float4 sv = seqrow[uu];
#pragma unroll
                for (int t = 0; t < TG; ++t)
#pragma unroll
                    for (int r = 0; r < kR; ++r) {
                        float4 rv = ((const float4*)(ri + (t * kR + r) * kD))[uu];
                        a[t][r] += sv.x * rv.x + sv.y * rv.y + sv.z * rv.z + sv.w * rv.w;
                    }
            }
#pragma unroll
            for (int t = 0; t < TG; ++t)
#pragma unroll
                for (int r = 0; r < kR; ++r)
                    att[t][r][s] = valid ? a[t][r] : -INFINITY;
        }
    }
    __syncthreads();

    // ---- P2: masked softmax * decay, in place; wave w owns t=w
#pragma unroll
    for (int r = 0; r < kR; ++r) {
        float* row = &att[wave][r][0];
        float a0 = row[lane];
        float a1 = row[lane + 64];
        float a2 = row[lane + 128];
        float a3 = (lane < kS - 192) ? row[lane + 192] : -INFINITY;
        float m = fmaxf(fmaxf(a0, a1), fmaxf(a2, a3));
#pragma unroll
        for (int off = 32; off; off >>= 1) m = fmaxf(m, __shfl_xor(m, off));
        float e0 = __expf(a0 - m), e1 = __expf(a1 - m), e2 = __expf(a2 - m);
        float e3 = (lane < kS - 192) ? __expf(a3 - m) : 0.f;
        float ssum = e0 + e1 + e2 + e3;
#pragma unroll
        for (int off = 32; off; off >>= 1) ssum += __shfl_xor(ssum, off);
        const float inv = 1.0f / ssum;
        row[lane]       = e0 * inv * dec[r][lane];
        row[lane + 64]  = e1 * inv * dec[r][lane + 64];
        row[lane + 128] = e2 * inv * dec[r][lane + 128];
        if (lane < kS - 192)
            row[lane + 192] = e3 * inv * dec[r][lane + 192];
    }
    // no barrier: P3 wave w reads only att[w][...] which wave w wrote (lgkmcnt order)

    // ---- P3: context for t=wave; lane = d
    {
        float acc[kR];
#pragma unroll
        for (int r = 0; r < kR; ++r) acc[r] = 0.f;
        const float* seqb = seq + (size_t)b * kS * kD + lane;
        for (int s0 = 0; s0 < kS; s0 += 4) {
            float4 av[kR];
#pragma unroll
            for (int r = 0; r < kR; ++r)
                av[r] = *(const float4*)&att[wave][r][s0];
            float sv0 = seqb[(size_t)(s0 + 0) * kD];
            float sv1 = seqb[(size_t)(s0 + 1) * kD];
            float sv2 = seqb[(size_t)(s0 + 2) * kD];
            float sv3 = seqb[(size_t)(s0 + 3) * kD];
#pragma unroll
            for (int r = 0; r < kR; ++r)
                acc[r] += sv0 * av[r].x + sv1 * av[r].y + sv2 * av[r].z + sv3 * av[r].w;
        }
        float* ob = out + (size_t)(bt0 + wave) * kR * kD;
#pragma unroll
        for (int r = 0; r < kR; ++r)
            ob[r * kD + lane] = acc[r];
    }
}

extern "C" void kernel_launch(void* const* d_in, const int* in_sizes, int n_in,
                              void* d_out, int out_size, void* d_ws, size_t ws_size,
                              hipStream_t stream) {
    const float* seq    = (const float*)d_in[0];
    const float* dt     = (const float*)d_in[1];
    const float* target = (const float*)d_in[2];
    const float* tv     = (const float*)d_in[3];
    const int*   vm     = (const int*)  d_in[4];
    const float* rel    = (const float*)d_in[5];
    const float* fr     = (const float*)d_in[6];
    const float* fi     = (const float*)d_in[7];
    float* out = (float*)d_out;

    rda_fused<<<kB * (kT / TG), 256, 0, stream>>>(seq, dt, target, tv, vm, rel, fr, fi, out);
}